// Round 15
// baseline (363.049 us; speedup 1.0000x reference)
//
#include <hip/hip_runtime.h>
#include <hip/hip_fp16.h>
#include <math.h>

#define Bb 2
#define Hh 8
#define Tt 4096
#define Kk 128
#define Vv 128
#define Ss 128
#define Cc 32
#define BH (Bb*Hh)
#define SCALE 0.08838834764831845f  /* 1/sqrt(128) */

// ---- workspace layout (float indices) ----
#define OFF_LFACC  0                               // BH*Tt
#define OFF_LFLAST (OFF_LFACC + BH*Tt)             // BH*Cc
#define OFF_MINTRA (OFF_LFLAST + BH*Cc)
#define OFF_KSUM   (OFF_MINTRA + BH*Cc)            // BH*Cc*Kk (fp32 -> n_prev)
#define OFF_KVH    (OFF_KSUM + BH*Cc*Kk)           // fp16 kv^T [blk][v][k^sw] SWIZZLED
#define OFF_KIMG   (OFF_KVH + BH*Cc*Kk*Vv/2)       // fp16 K image [blk][t][k^sw]
#define OFF_CNT    (OFF_KIMG + BH*Tt*Kk/2)         // 2 x u32 barrier counters

typedef _Float16 f16x8 __attribute__((ext_vector_type(8)));
typedef _Float16 f16x4 __attribute__((ext_vector_type(4)));
typedef _Float16 f16x2 __attribute__((ext_vector_type(2)));
typedef float f32x4 __attribute__((ext_vector_type(4)));

union U2 { f16x2 h; unsigned u; };
union U8 { f16x8 v; unsigned u[4]; };

#define GLDS16(gp, lp) __builtin_amdgcn_global_load_lds( \
    (const __attribute__((address_space(1))) void*)(gp), \
    (__attribute__((address_space(3))) void*)(lp), 16, 0, 0)

// Device-scope grid barrier. Co-residency guaranteed by capacity:
// 256 blocks, 1 block/CU (LDS 133KB), 256 CUs. Timeout (~40ms) converts any
// barrier malfunction into a wrong-output FAIL instead of a hang.
__device__ __forceinline__ void grid_bar(unsigned* cnt, unsigned target) {
    __threadfence();
    __syncthreads();
    if (threadIdx.x == 0) {
        __hip_atomic_fetch_add(cnt, 1u, __ATOMIC_ACQ_REL, __HIP_MEMORY_SCOPE_AGENT);
        unsigned long long t0 = __builtin_amdgcn_s_memrealtime();
        while (__hip_atomic_load(cnt, __ATOMIC_ACQUIRE, __HIP_MEMORY_SCOPE_AGENT) < target) {
            __builtin_amdgcn_s_sleep(8);
            if (__builtin_amdgcn_s_memrealtime() - t0 > 4000000ull) break;
        }
    }
    __syncthreads();
}

// ---------------------------------------------------------------------------
// Fused kernel: 256 blocks x 1024 threads, each block = 2 chunk-halves.
// Phase A (gates+kv^T+ksum+kimg) -> grid_bar -> Phase B (scan) -> grid_bar ->
// Phase C (intra+output). V^T stays RESIDENT in LDS from A to C (vimg
// round-trip eliminated); kimg reused same-CU L2-hot.
// ---------------------------------------------------------------------------
__global__ __launch_bounds__(1024, 4) void k_fused(const float* __restrict__ qg,
                                                   const float* __restrict__ kg,
                                                   const float* __restrict__ vg,
                                                   const float* __restrict__ ig,
                                                   const float* __restrict__ fg,
                                                   const float* __restrict__ C0,
                                                   const float* __restrict__ n0,
                                                   const float* __restrict__ m0,
                                                   float* __restrict__ out,
                                                   float* __restrict__ ws) {
    __shared__ _Float16 XA[2][Ss * Kk];  // A: (g*K)^T | C: K img -> c_prev^T
    __shared__ _Float16 XB[2][Ss * Kk];  // A: V^T      | C: V^T (RESIDENT)
    __shared__ float sbt[2][Ss];         // A: sfg | C: bt
    __shared__ float sas[2][Ss], siw[2][Ss], slfa[2][Ss], snp[2][Ss];
    __shared__ float scomb[2][4];

    int tid  = threadIdx.x;
    int half = tid >> 9;
    int t512 = tid & 511;
    int vb   = blockIdx.x * 2 + half;     // virtual block = (bh, c)
    int bh = vb >> 5;
    int c  = vb & 31;
    int lane = tid & 63;
    int w = t512 >> 6;                    // wave-in-half 0..7
    int l15 = lane & 15;
    int g = lane >> 4;

    unsigned* cnt = (unsigned*)(ws + OFF_CNT);
    const float* kb = kg + ((size_t)bh * Tt + (size_t)c * Ss) * Kk;
    const float* vbp = vg + ((size_t)bh * Tt + (size_t)c * Ss) * Vv;
    _Float16* kimgw = (_Float16*)(ws + OFF_KIMG) + (size_t)vb * Ss * Kk;

    // ================= PHASE A =================
    {
        int c0a = (t512 & 31) * 4;
        int t0a = (t512 >> 5) * 4;
        const float* ksrcA = kb + (size_t)t0a * Kk + c0a;
        const float* vsrcA = vbp + (size_t)t0a * Vv + c0a;
        float4 kA0 = *(const float4*)(ksrcA);
        float4 kA1 = *(const float4*)(ksrcA + Kk);
        float4 kA2 = *(const float4*)(ksrcA + 2 * Kk);
        float4 kA3 = *(const float4*)(ksrcA + 3 * Kk);
        float4 vA0 = *(const float4*)(vsrcA);
        float4 vA1 = *(const float4*)(vsrcA + Vv);
        float4 vA2 = *(const float4*)(vsrcA + 2 * Vv);
        float4 vA3 = *(const float4*)(vsrcA + 3 * Vv);
        int tau1 = t512 + 512;
        int c0b = (tau1 & 31) * 4;
        int t0b = (tau1 >> 5) * 4;
        const float* ksrcB = kb + (size_t)t0b * Kk + c0b;
        const float* vsrcB = vbp + (size_t)t0b * Vv + c0b;
        float4 kB0 = *(const float4*)(ksrcB);
        float4 kB1 = *(const float4*)(ksrcB + Kk);
        float4 kB2 = *(const float4*)(ksrcB + 2 * Kk);
        float4 kB3 = *(const float4*)(ksrcB + 3 * Kk);
        float4 vB0 = *(const float4*)(vsrcB);
        float4 vB1 = *(const float4*)(vsrcB + Vv);
        float4 vB2 = *(const float4*)(vsrcB + 2 * Vv);
        float4 vB3 = *(const float4*)(vsrcB + 3 * Vv);

        // K image export (pre-swizzled [t][k^((t&15)<<3)]) — above gates
#pragma unroll
        for (int jr = 0; jr < 4; jr++) {
            float4 kr4 = (jr == 0 ? kA0 : jr == 1 ? kA1 : jr == 2 ? kA2 : kA3);
            int t = t0a + jr;
            int col = c0a ^ ((t & 15) << 3);
            f16x4 h = { (_Float16)kr4.x, (_Float16)kr4.y, (_Float16)kr4.z, (_Float16)kr4.w };
            *(f16x4*)&kimgw[(size_t)t * Kk + col] = h;
        }
#pragma unroll
        for (int jr = 0; jr < 4; jr++) {
            float4 kr4 = (jr == 0 ? kB0 : jr == 1 ? kB1 : jr == 2 ? kB2 : kB3);
            int t = t0b + jr;
            int col = c0b ^ ((t & 15) << 3);
            f16x4 h = { (_Float16)kr4.x, (_Float16)kr4.y, (_Float16)kr4.z, (_Float16)kr4.w };
            *(f16x4*)&kimgw[(size_t)t * Kk + col] = h;
        }

        // gates (t512 0..127 per half, shfl-based scan)
        bool p0 = t512 < Ss;
        int lane64 = t512 & 63;
        int wv = (t512 >> 6) & 1;
        int gidx = bh * Tt + c * Ss + t512;
        float lfacc = 0.f, fwd = 0.f;
        if (p0) {
            float x  = fg[gidx];
            lfacc = fminf(x, 0.f) - log1pf(__expf(-fabsf(x)));
            for (int off = 1; off < 64; off <<= 1) {
                float o = __shfl_up(lfacc, off);
                if (lane64 >= off) lfacc += o;
            }
            if (lane64 == 63) scomb[half][wv] = lfacc;
        }
        __syncthreads();
        if (p0) {
            float tot0 = scomb[half][0];
            if (wv == 1) lfacc += tot0;
            float lflast = tot0 + scomb[half][1];
            fwd = ig[gidx] + lflast - lfacc;
            float mx = fwd;
            for (int off = 32; off; off >>= 1) mx = fmaxf(mx, __shfl_xor(mx, off));
            if (lane64 == 0) scomb[half][2 + wv] = mx;
        }
        __syncthreads();
        if (p0) {
            float mi = fmaxf(scomb[half][2], scomb[half][3]);
            sbt[half][t512] = __expf(fwd - mi);
            ws[OFF_LFACC + gidx] = lfacc;
            if (t512 == 0) {
                ws[OFF_LFLAST + vb] = scomb[half][0] + scomb[half][1];
                ws[OFF_MINTRA + vb] = mi;
            }
        }
        __syncthreads();

        // stage rep0
        {
            float g0 = sbt[half][t0a], g1 = sbt[half][t0a + 1],
                  g2 = sbt[half][t0a + 2], g3 = sbt[half][t0a + 3];
#pragma unroll
            for (int jc = 0; jc < 4; jc++) {
                float ke0 = (jc == 0 ? kA0.x : jc == 1 ? kA0.y : jc == 2 ? kA0.z : kA0.w);
                float ke1 = (jc == 0 ? kA1.x : jc == 1 ? kA1.y : jc == 2 ? kA1.z : kA1.w);
                float ke2 = (jc == 0 ? kA2.x : jc == 1 ? kA2.y : jc == 2 ? kA2.z : kA2.w);
                float ke3 = (jc == 0 ? kA3.x : jc == 1 ? kA3.y : jc == 2 ? kA3.z : kA3.w);
                float ve0 = (jc == 0 ? vA0.x : jc == 1 ? vA0.y : jc == 2 ? vA0.z : vA0.w);
                float ve1 = (jc == 0 ? vA1.x : jc == 1 ? vA1.y : jc == 2 ? vA1.z : vA1.w);
                float ve2 = (jc == 0 ? vA2.x : jc == 1 ? vA2.y : jc == 2 ? vA2.z : vA2.w);
                float ve3 = (jc == 0 ? vA3.x : jc == 1 ? vA3.y : jc == 2 ? vA3.z : vA3.w);
                int row = c0a + jc;
                int col = t0a ^ ((row & 15) << 3);
                f16x4 kc = { (_Float16)(ke0 * g0), (_Float16)(ke1 * g1),
                             (_Float16)(ke2 * g2), (_Float16)(ke3 * g3) };
                f16x4 vc = { (_Float16)ve0, (_Float16)ve1, (_Float16)ve2, (_Float16)ve3 };
                *(f16x4*)&XA[half][row * Ss + col] = kc;
                *(f16x4*)&XB[half][row * Ss + col] = vc;
            }
        }
        // stage rep1
        {
            float g0 = sbt[half][t0b], g1 = sbt[half][t0b + 1],
                  g2 = sbt[half][t0b + 2], g3 = sbt[half][t0b + 3];
#pragma unroll
            for (int jc = 0; jc < 4; jc++) {
                float ke0 = (jc == 0 ? kB0.x : jc == 1 ? kB0.y : jc == 2 ? kB0.z : kB0.w);
                float ke1 = (jc == 0 ? kB1.x : jc == 1 ? kB1.y : jc == 2 ? kB1.z : kB1.w);
                float ke2 = (jc == 0 ? kB2.x : jc == 1 ? kB2.y : jc == 2 ? kB2.z : kB2.w);
                float ke3 = (jc == 0 ? kB3.x : jc == 1 ? kB3.y : jc == 2 ? kB3.z : kB3.w);
                float ve0 = (jc == 0 ? vB0.x : jc == 1 ? vB0.y : jc == 2 ? vB0.z : vB0.w);
                float ve1 = (jc == 0 ? vB1.x : jc == 1 ? vB1.y : jc == 2 ? vB1.z : vB1.w);
                float ve2 = (jc == 0 ? vB2.x : jc == 1 ? vB2.y : jc == 2 ? vB2.z : vB2.w);
                float ve3 = (jc == 0 ? vB3.x : jc == 1 ? vB3.y : jc == 2 ? vB3.z : vB3.w);
                int row = c0b + jc;
                int col = t0b ^ ((row & 15) << 3);
                f16x4 kc = { (_Float16)(ke0 * g0), (_Float16)(ke1 * g1),
                             (_Float16)(ke2 * g2), (_Float16)(ke3 * g3) };
                f16x4 vc = { (_Float16)ve0, (_Float16)ve1, (_Float16)ve2, (_Float16)ve3 };
                *(f16x4*)&XA[half][row * Ss + col] = kc;
                *(f16x4*)&XB[half][row * Ss + col] = vc;
            }
        }
        __syncthreads();

        // ksum (t512 0..127)
        if (p0) {
            int sw = (t512 & 15) << 3;
            float s = 0.f;
#pragma unroll
            for (int i = 0; i < 16; i++) {
                f16x8 ld = *(const f16x8*)&XA[half][t512 * Ss + ((8 * i) ^ sw)];
#pragma unroll
                for (int e = 0; e < 8; e++) s += (float)ld[e];
            }
            ws[OFF_KSUM + (size_t)vb * Kk + t512] = s;
        }

        // MFMA (swapped): wave w -> vidx band [16w, 16w+16)
        const int band = w * 16;
        const int swt = l15 << 3;
        f16x8 af[4];
#pragma unroll
        for (int kk = 0; kk < 4; kk++)
            af[kk] = *(const f16x8*)&XB[half][(band + l15) * Ss + ((kk * 32 + g * 8) ^ swt)];

        f32x4 acc[8];
#pragma unroll
        for (int kj = 0; kj < 8; kj++) acc[kj] = (f32x4){0.f, 0.f, 0.f, 0.f};

#pragma unroll
        for (int kj = 0; kj < 8; kj++) {
            int kr = kj * 16 + l15;
#pragma unroll
            for (int kk = 0; kk < 4; kk++) {
                f16x8 bv = *(const f16x8*)&XA[half][kr * Ss + ((kk * 32 + g * 8) ^ swt)];
                acc[kj] = __builtin_amdgcn_mfma_f32_16x16x32_f16(af[kk], bv, acc[kj], 0, 0, 0);
            }
        }

        _Float16* dst = (_Float16*)(ws + OFF_KVH) + (size_t)vb * Kk * Vv;
#pragma unroll
        for (int kj = 0; kj < 8; kj++)
#pragma unroll
            for (int r = 0; r < 4; r++) {
                int vrow = band + 4 * g + r;
                int col = (kj * 16 + l15) ^ ((vrow & 15) << 3);
                dst[(size_t)vrow * Kk + col] = (_Float16)acc[kj][r];
            }
    }

    grid_bar(&cnt[0], 256);

    // ================= PHASE B: inter-chunk scan =================
    {
        const int NC2 = BH * Kk * Vv / 2;     // 131072 chains (8192-aligned)
        int gtid = blockIdx.x * 1024 + tid;
        int l32 = lane & 31;
        if (gtid < NC2) {
            int bh2 = gtid >> 13;             // wave-uniform
            float m   = m0[bh2];
            float lfl = ws[OFF_LFLAST + bh2 * Cc + l32];
            float mi  = ws[OFF_MINTRA + bh2 * Cc + l32];
            float mn  = fmaxf(lfl + m, mi);
            float e1l = __expf(lfl + m - mn);
            float e2l = __expf(mi - mn);
            int i  = gtid & 8191;
            int vv_ = i >> 6;
            int j2 = (i & 63) << 1;
            int klog = j2 ^ ((vv_ & 15) << 3);
            float st0 = C0[(size_t)bh2 * Kk * Vv + (size_t)klog * Vv + vv_];
            float st1 = C0[(size_t)bh2 * Kk * Vv + (size_t)(klog + 1) * Vv + vv_];
            f16x2* base = (f16x2*)((_Float16*)(ws + OFF_KVH) +
                                   (size_t)bh2 * Cc * Kk * Vv + (size_t)vv_ * Kk + j2);
            const size_t stride = Kk * Vv / 2;
            f16x2 cur = base[0];
            f16x2 nxt = base[stride];
#pragma unroll
            for (int cc = 0; cc < Cc; cc++) {
                f16x2 n2 = (cc + 2 < Cc) ? base[(size_t)(cc + 2) * stride]
                                         : (f16x2){(_Float16)0.f, (_Float16)0.f};
                f16x2 o = { (_Float16)st0, (_Float16)st1 };
                base[(size_t)cc * stride] = o;
                float e1 = __shfl(e1l, cc);
                float e2 = __shfl(e2l, cc);
                st0 = st0 * e1 + (float)cur[0] * e2;
                st1 = st1 * e1 + (float)cur[1] * e2;
                cur = nxt; nxt = n2;
            }
        } else if (gtid < NC2 + BH * Kk) {
            int g2 = gtid - NC2;
            int bh2 = g2 >> 7;                // wave-uniform
            float m   = m0[bh2];
            float lfl = ws[OFF_LFLAST + bh2 * Cc + l32];
            float mi  = ws[OFF_MINTRA + bh2 * Cc + l32];
            float mn  = fmaxf(lfl + m, mi);
            float e1l = __expf(lfl + m - mn);
            float e2l = __expf(mi - mn);
            float st = n0[g2];
            float* base = ws + OFF_KSUM + (size_t)bh2 * Cc * Kk + (g2 & (Kk - 1));
            float cur = base[0];
            float nxt = base[Kk];
#pragma unroll
            for (int cc = 0; cc < Cc; cc++) {
                float n2 = (cc + 2 < Cc) ? base[(size_t)(cc + 2) * Kk] : 0.f;
                float kvv = cur;
                base[(size_t)cc * Kk] = st;
                st = st * __shfl(e1l, cc) + kvv * __shfl(e2l, cc);
                cur = nxt; nxt = n2;
            }
        }
    }

    grid_bar(&cnt[1], 256);

    // ================= PHASE C: intra-chunk scores + output =================
    {
        const int S0 = w * 16;
        const int swt = l15 << 3;
        const size_t rowbase = (size_t)bh * Tt + (size_t)c * Ss;
        const float* qp = qg + rowbase * Kk;
        const float* nprev = ws + OFF_KSUM + (size_t)vb * Kk;
        const _Float16* cprevT = (const _Float16*)(ws + OFF_KVH) + (size_t)vb * Kk * Vv;
        const _Float16* kimg = (const _Float16*)(ws + OFF_KIMG) + (size_t)vb * Ss * Kk;
        const float m_prev = m0[bh];

        // async K image load into XA (V^T already RESIDENT in XB)
#pragma unroll
        for (int p = 0; p < 4; p++) {
            int unit = p * 512 + w * 64;                 // wave-uniform per half
            GLDS16(kimg + (size_t)(unit + lane) * 8, &XA[half][unit * 8]);
        }

        // Q fragments
        f16x8 qf[4];
#pragma unroll
        for (int kk = 0; kk < 4; kk++) {
            const float* p = qp + (size_t)(S0 + l15) * Kk + kk * 32 + g * 8;
            float4 a = *(const float4*)p;
            float4 b = *(const float4*)(p + 4);
            f16x8 r;
            r[0]=(_Float16)a.x; r[1]=(_Float16)a.y; r[2]=(_Float16)a.z; r[3]=(_Float16)a.w;
            r[4]=(_Float16)b.x; r[5]=(_Float16)b.y; r[6]=(_Float16)b.z; r[7]=(_Float16)b.w;
            qf[kk] = r;
        }

        // bt + prefix max (t512 0..127)
        bool p0 = t512 < Ss;
        int lane64 = t512 & 63;
        int wv = (t512 >> 6) & 1;
        float pm = 0.f;
        if (p0) {
            float lfa = ws[OFF_LFACC + bh * Tt + c * Ss + t512];
            float bt = ig[bh * Tt + c * Ss + t512] - lfa;
            sbt[half][t512] = bt;
            slfa[half][t512] = lfa;
            snp[half][t512] = nprev[t512];
            pm = bt;
            for (int off = 1; off < 64; off <<= 1) {
                float o = __shfl_up(pm, off);
                if (lane64 >= off) pm = fmaxf(pm, o);
            }
            if (lane64 == 63) scomb[half][wv] = pm;
        }
        __syncthreads();   // barrier A

        if (p0) {
            if (wv == 1) pm = fmaxf(pm, scomb[half][0]);
            float mx = fmaxf(pm, m_prev);
            sas[half][t512] = -mx;
            siw[half][t512] = SCALE * __expf(m_prev - mx);
        }
        float dotq = 0.f;
#pragma unroll
        for (int kk = 0; kk < 4; kk++)
#pragma unroll
            for (int e = 0; e < 8; e++)
                dotq += (float)qf[kk][e] * snp[half][kk * 32 + g * 8 + e];
        dotq += __shfl_xor(dotq, 16);
        dotq += __shfl_xor(dotq, 32);
        __syncthreads();   // barrier B

        const float as_s = sas[half][S0 + l15];
        const float iw_s = siw[half][S0 + l15];
        const float lfa_s = slfa[half][S0 + l15];

        // swapped QK^T
        unsigned plo[8] = {0,0,0,0,0,0,0,0};
        unsigned phi[8] = {0,0,0,0,0,0,0,0};
        float rs = 0.f;
#pragma unroll
        for (int tj = 0; tj < 8; tj++) {
            if (tj <= w) {
                int trow = tj * 16 + l15;
                f16x8 bfr[4];
#pragma unroll
                for (int kk = 0; kk < 4; kk++)
                    bfr[kk] = *(const f16x8*)&XA[half][trow * Kk + ((kk * 32 + g * 8) ^ swt)];
                f32x4 acc = {0.f, 0.f, 0.f, 0.f};
#pragma unroll
                for (int kk = 0; kk < 4; kk++)
                    acc = __builtin_amdgcn_mfma_f32_16x16x32_f16(bfr[kk], qf[kk], acc, 0, 0, 0);
                float vals[4];
#pragma unroll
                for (int r = 0; r < 4; r++) {
                    int t = tj * 16 + 4 * g + r;
                    float btv = sbt[half][t];
                    float val = acc[r] * SCALE * __expf(as_s + btv);
                    if (tj == w && (4 * g + r) > l15) val = 0.f;   // causal mask
                    rs += val;
                    vals[r] = val;
                }
                U2 lo, hi;
                lo.h = (f16x2){ (_Float16)vals[0], (_Float16)vals[1] };
                hi.h = (f16x2){ (_Float16)vals[2], (_Float16)vals[3] };
                plo[tj] = lo.u;
                phi[tj] = hi.u;
            }
        }
        rs += __shfl_xor(rs, 16);
        rs += __shfl_xor(rs, 32);
        float engs = __expf(as_s - lfa_s);
        float rnv_s = 1.0f / fmaxf(fabsf(rs + dotq * iw_s), engs);
        __syncthreads();   // barrier C: QK^T reads of XA done

        // stage c_prev^T into XA (async; hidden under pb + PV)
#pragma unroll
        for (int p = 0; p < 4; p++) {
            int u = w * 4 + p;
            GLDS16(cprevT + (size_t)(u * 64 + lane) * 8, &XA[half][u * 512]);
        }

        // P -> B-operand fragments via cross-g shfl exchange
        f16x8 pb[4];
        const int kmax = w >> 1;
        {
            int a2 = (g & 1) * 2;
            int sAl = a2 * 16 + l15;
            int sBl = sAl + 16;
            bool hi2 = (g >> 1) != 0;
#pragma unroll
            for (int kkt = 0; kkt < 4; kkt++) {
                if (kkt <= kmax) {
                    unsigned xA0 = __shfl((int)plo[2*kkt],   sAl);
                    unsigned xA1 = __shfl((int)phi[2*kkt],   sAl);
                    unsigned xB0 = __shfl((int)plo[2*kkt],   sBl);
                    unsigned xB1 = __shfl((int)phi[2*kkt],   sBl);
                    unsigned yA0 = __shfl((int)plo[2*kkt+1], sAl);
                    unsigned yA1 = __shfl((int)phi[2*kkt+1], sAl);
                    unsigned yB0 = __shfl((int)plo[2*kkt+1], sBl);
                    unsigned yB1 = __shfl((int)phi[2*kkt+1], sBl);
                    U8 t;
                    t.u[0] = hi2 ? yA0 : xA0;
                    t.u[1] = hi2 ? yA1 : xA1;
                    t.u[2] = hi2 ? yB0 : xB0;
                    t.u[3] = hi2 ? yB1 : xB1;
                    pb[kkt] = t.v;
                }
            }
        }

        // PV for BOTH halves of v (reads resident XB)
        f32x4 h4[2][4];
#pragma unroll
        for (int hv = 0; hv < 2; hv++)
#pragma unroll
            for (int j = 0; j < 4; j++) h4[hv][j] = (f32x4){0.f, 0.f, 0.f, 0.f};

#pragma unroll
        for (int kkt = 0; kkt < 4; kkt++) {
            if (kkt <= kmax) {
#pragma unroll
                for (int hv = 0; hv < 2; hv++)
#pragma unroll
                    for (int j = 0; j < 4; j++) {
                        int vr = (hv * 4 + j) * 16 + l15;
                        f16x8 av = *(const f16x8*)&XB[half][vr * Ss + ((kkt * 32 + g * 8) ^ swt)];
                        h4[hv][j] = __builtin_amdgcn_mfma_f32_16x16x32_f16(av, pb[kkt], h4[hv][j], 0, 0, 0);
                    }
            }
        }

        asm volatile("s_waitcnt vmcnt(0)" ::: "memory");
        __syncthreads();   // barrier D: c_prev^T staged in XA

        // inter (LDS, swizzled) + combine + float4 stores
#pragma unroll
        for (int hv = 0; hv < 2; hv++)
#pragma unroll
            for (int j = 0; j < 4; j++) {
                int vr = (hv * 4 + j) * 16 + l15;
                f32x4 tmp = {0.f, 0.f, 0.f, 0.f};
                int swv = (vr & 15) << 3;
#pragma unroll
                for (int kk = 0; kk < 4; kk++) {
                    f16x8 bcf = *(const f16x8*)&XA[half][vr * Kk + ((kk * 32 + g * 8) ^ swv)];
                    tmp = __builtin_amdgcn_mfma_f32_16x16x32_f16(bcf, qf[kk], tmp, 0, 0, 0);
                }
                float4 o;
                o.x = (h4[hv][j][0] + tmp[0] * iw_s) * rnv_s;
                o.y = (h4[hv][j][1] + tmp[1] * iw_s) * rnv_s;
                o.z = (h4[hv][j][2] + tmp[2] * iw_s) * rnv_s;
                o.w = (h4[hv][j][3] + tmp[3] * iw_s) * rnv_s;
                *(float4*)&out[(rowbase + S0 + l15) * Vv + (hv * 4 + j) * 16 + 4 * g] = o;
            }
    }
}

// ---------------------------------------------------------------------------
extern "C" void kernel_launch(void* const* d_in, const int* in_sizes, int n_in,
                              void* d_out, int out_size, void* d_ws, size_t ws_size,
                              hipStream_t stream) {
    (void)in_sizes; (void)n_in; (void)out_size; (void)ws_size;
    const float* q  = (const float*)d_in[0];
    const float* k  = (const float*)d_in[1];
    const float* v  = (const float*)d_in[2];
    const float* ig = (const float*)d_in[3];
    const float* fg = (const float*)d_in[4];
    const float* C0 = (const float*)d_in[5];
    const float* n0 = (const float*)d_in[6];
    const float* m0 = (const float*)d_in[7];
    float* out = (float*)d_out;
    float* ws  = (float*)d_ws;

    // zero the barrier counters every launch (graph-capturable)
    hipMemsetAsync((char*)d_ws + (size_t)OFF_CNT * sizeof(float), 0, 8, stream);
    k_fused<<<256, 1024, 0, stream>>>(q, k, v, ig, fg, C0, n0, m0, out, ws);
}

// Round 16
// 53.040 us; speedup vs baseline: 6.8448x; 6.8448x over previous
//
#include <hip/hip_runtime.h>
#include <hip/hip_fp16.h>
#include <math.h>

#define Bb 2
#define Hh 8
#define Tt 4096
#define Kk 128
#define Vv 128
#define Ss 128
#define Cc 32
#define BH (Bb*Hh)
#define SCALE 0.08838834764831845f  /* 1/sqrt(128) */

// ---- workspace layout (float indices) ----
#define OFF_LFACC  0                               // BH*Tt
#define OFF_LFLAST (OFF_LFACC + BH*Tt)             // BH*Cc
#define OFF_MINTRA (OFF_LFLAST + BH*Cc)
#define OFF_KSUM   (OFF_MINTRA + BH*Cc)            // BH*Cc*Kk (fp32 -> n_prev)
#define OFF_KVH    (OFF_KSUM + BH*Cc*Kk)           // fp16 kv^T [blk][v][k^sw] SWIZZLED
#define OFF_KIMG   (OFF_KVH + BH*Cc*Kk*Vv/2)       // fp16 K image [blk][t][k^sw]
#define OFF_VIMG   (OFF_KIMG + BH*Tt*Kk/2)         // fp16 V^T image [blk][v][t^sw]

typedef _Float16 f16x8 __attribute__((ext_vector_type(8)));
typedef _Float16 f16x4 __attribute__((ext_vector_type(4)));
typedef _Float16 f16x2 __attribute__((ext_vector_type(2)));
typedef float f32x4 __attribute__((ext_vector_type(4)));

union U2 { f16x2 h; unsigned u; };
union U8 { f16x8 v; unsigned u[4]; };

#define GLDS16(gp, lp) __builtin_amdgcn_global_load_lds( \
    (const __attribute__((address_space(1))) void*)(gp), \
    (__attribute__((address_space(3))) void*)(lp), 16, 0, 0)

// ---------------------------------------------------------------------------
// Kernel 1: fused gates + MFMA kv^T (fp16, swizzled) + ksum + K/V^T images.
// 512 threads, 8 waves. All staging loads hoisted; kimg export above gates.
// ---------------------------------------------------------------------------
__global__ __launch_bounds__(512, 4) void k_kvg(const float* __restrict__ ig,
                                                const float* __restrict__ fg,
                                                const float* __restrict__ kg,
                                                const float* __restrict__ vg,
                                                float* __restrict__ ws) {
    __shared__ _Float16 Kt[Ss * Ss];   // (g*K)^T [kidx][t], swizzled
    __shared__ _Float16 Vt[Ss * Ss];   // V^T [vidx][t], swizzled
    __shared__ float sfg[Ss];
    __shared__ float scomb[4];

    int blk = blockIdx.x;
    int bh = blk >> 5;
    int c  = blk & 31;
    int tid = threadIdx.x;
    int lane = tid & 63;
    int w = tid >> 6;
    int l15 = lane & 15;
    int g = lane >> 4;

    const float* kb = kg + ((size_t)bh * Tt + (size_t)c * Ss) * Kk;
    const float* vb = vg + ((size_t)bh * Tt + (size_t)c * Ss) * Vv;
    _Float16* kimgw = (_Float16*)(ws + OFF_KIMG) + (size_t)blk * Ss * Kk;
    _Float16* vimgw = (_Float16*)(ws + OFF_VIMG) + (size_t)blk * Ss * Kk;

    // ---- hoisted staging loads, BOTH reps ----
    int c0a = (tid & 31) * 4;
    int t0a = (tid >> 5) * 4;
    const float* ksrcA = kb + (size_t)t0a * Kk + c0a;
    const float* vsrcA = vb + (size_t)t0a * Vv + c0a;
    float4 kA0 = *(const float4*)(ksrcA);
    float4 kA1 = *(const float4*)(ksrcA + Kk);
    float4 kA2 = *(const float4*)(ksrcA + 2 * Kk);
    float4 kA3 = *(const float4*)(ksrcA + 3 * Kk);
    float4 vA0 = *(const float4*)(vsrcA);
    float4 vA1 = *(const float4*)(vsrcA + Vv);
    float4 vA2 = *(const float4*)(vsrcA + 2 * Vv);
    float4 vA3 = *(const float4*)(vsrcA + 3 * Vv);
    int tau1 = tid + 512;
    int c0b = (tau1 & 31) * 4;
    int t0b = (tau1 >> 5) * 4;
    const float* ksrcB = kb + (size_t)t0b * Kk + c0b;
    const float* vsrcB = vb + (size_t)t0b * Vv + c0b;
    float4 kB0 = *(const float4*)(ksrcB);
    float4 kB1 = *(const float4*)(ksrcB + Kk);
    float4 kB2 = *(const float4*)(ksrcB + 2 * Kk);
    float4 kB3 = *(const float4*)(ksrcB + 3 * Kk);
    float4 vB0 = *(const float4*)(vsrcB);
    float4 vB1 = *(const float4*)(vsrcB + Vv);
    float4 vB2 = *(const float4*)(vsrcB + 2 * Vv);
    float4 vB3 = *(const float4*)(vsrcB + 3 * Vv);

    // ---- K image export (pre-swizzled [t][k^((t&15)<<3)]) — above gates ----
#pragma unroll
    for (int jr = 0; jr < 4; jr++) {
        float4 kr4 = (jr == 0 ? kA0 : jr == 1 ? kA1 : jr == 2 ? kA2 : kA3);
        int t = t0a + jr;
        int col = c0a ^ ((t & 15) << 3);
        f16x4 h = { (_Float16)kr4.x, (_Float16)kr4.y, (_Float16)kr4.z, (_Float16)kr4.w };
        *(f16x4*)&kimgw[(size_t)t * Kk + col] = h;
    }
#pragma unroll
    for (int jr = 0; jr < 4; jr++) {
        float4 kr4 = (jr == 0 ? kB0 : jr == 1 ? kB1 : jr == 2 ? kB2 : kB3);
        int t = t0b + jr;
        int col = c0b ^ ((t & 15) << 3);
        f16x4 h = { (_Float16)kr4.x, (_Float16)kr4.y, (_Float16)kr4.z, (_Float16)kr4.w };
        *(f16x4*)&kimgw[(size_t)t * Kk + col] = h;
    }

    // ---- gates (threads 0..127, shfl-based scan) ----
    bool p0 = tid < Ss;
    int lane64 = tid & 63;
    int wv = (tid >> 6) & 1;
    int gidx = bh * Tt + c * Ss + tid;
    float lfacc = 0.f, fwd = 0.f;
    if (p0) {
        float x  = fg[gidx];
        lfacc = fminf(x, 0.f) - log1pf(__expf(-fabsf(x)));
        for (int off = 1; off < 64; off <<= 1) {
            float o = __shfl_up(lfacc, off);
            if (lane64 >= off) lfacc += o;
        }
        if (lane64 == 63) scomb[wv] = lfacc;
    }
    __syncthreads();
    if (p0) {
        float tot0 = scomb[0];
        if (wv == 1) lfacc += tot0;
        float lflast = tot0 + scomb[1];
        fwd = ig[gidx] + lflast - lfacc;
        float mx = fwd;
        for (int off = 32; off; off >>= 1) mx = fmaxf(mx, __shfl_xor(mx, off));
        if (lane64 == 0) scomb[2 + wv] = mx;
    }
    __syncthreads();
    if (p0) {
        float mi = fmaxf(scomb[2], scomb[3]);
        sfg[tid] = __expf(fwd - mi);
        ws[OFF_LFACC + gidx] = lfacc;
        if (tid == 0) {
            ws[OFF_LFLAST + blk] = scomb[0] + scomb[1];
            ws[OFF_MINTRA + blk] = mi;
        }
    }
    __syncthreads();

    // ---- stage rep0 ----
    {
        float g0 = sfg[t0a], g1 = sfg[t0a + 1], g2 = sfg[t0a + 2], g3 = sfg[t0a + 3];
#pragma unroll
        for (int jc = 0; jc < 4; jc++) {
            float ke0 = (jc == 0 ? kA0.x : jc == 1 ? kA0.y : jc == 2 ? kA0.z : kA0.w);
            float ke1 = (jc == 0 ? kA1.x : jc == 1 ? kA1.y : jc == 2 ? kA1.z : kA1.w);
            float ke2 = (jc == 0 ? kA2.x : jc == 1 ? kA2.y : jc == 2 ? kA2.z : kA2.w);
            float ke3 = (jc == 0 ? kA3.x : jc == 1 ? kA3.y : jc == 2 ? kA3.z : kA3.w);
            float ve0 = (jc == 0 ? vA0.x : jc == 1 ? vA0.y : jc == 2 ? vA0.z : vA0.w);
            float ve1 = (jc == 0 ? vA1.x : jc == 1 ? vA1.y : jc == 2 ? vA1.z : vA1.w);
            float ve2 = (jc == 0 ? vA2.x : jc == 1 ? vA2.y : jc == 2 ? vA2.z : vA2.w);
            float ve3 = (jc == 0 ? vA3.x : jc == 1 ? vA3.y : jc == 2 ? vA3.z : vA3.w);
            int row = c0a + jc;
            int col = t0a ^ ((row & 15) << 3);
            f16x4 kc = { (_Float16)(ke0 * g0), (_Float16)(ke1 * g1),
                         (_Float16)(ke2 * g2), (_Float16)(ke3 * g3) };
            f16x4 vc = { (_Float16)ve0, (_Float16)ve1, (_Float16)ve2, (_Float16)ve3 };
            *(f16x4*)&Kt[row * Ss + col] = kc;
            *(f16x4*)&Vt[row * Ss + col] = vc;
        }
    }
    // ---- stage rep1 ----
    {
        float g0 = sfg[t0b], g1 = sfg[t0b + 1], g2 = sfg[t0b + 2], g3 = sfg[t0b + 3];
#pragma unroll
        for (int jc = 0; jc < 4; jc++) {
            float ke0 = (jc == 0 ? kB0.x : jc == 1 ? kB0.y : jc == 2 ? kB0.z : kB0.w);
            float ke1 = (jc == 0 ? kB1.x : jc == 1 ? kB1.y : jc == 2 ? kB1.z : kB1.w);
            float ke2 = (jc == 0 ? kB2.x : jc == 1 ? kB2.y : jc == 2 ? kB2.z : kB2.w);
            float ke3 = (jc == 0 ? kB3.x : jc == 1 ? kB3.y : jc == 2 ? kB3.z : kB3.w);
            float ve0 = (jc == 0 ? vB0.x : jc == 1 ? vB0.y : jc == 2 ? vB0.z : vB0.w);
            float ve1 = (jc == 0 ? vB1.x : jc == 1 ? vB1.y : jc == 2 ? vB1.z : vB1.w);
            float ve2 = (jc == 0 ? vB2.x : jc == 1 ? vB2.y : jc == 2 ? vB2.z : vB2.w);
            float ve3 = (jc == 0 ? vB3.x : jc == 1 ? vB3.y : jc == 2 ? vB3.z : vB3.w);
            int row = c0b + jc;
            int col = t0b ^ ((row & 15) << 3);
            f16x4 kc = { (_Float16)(ke0 * g0), (_Float16)(ke1 * g1),
                         (_Float16)(ke2 * g2), (_Float16)(ke3 * g3) };
            f16x4 vc = { (_Float16)ve0, (_Float16)ve1, (_Float16)ve2, (_Float16)ve3 };
            *(f16x4*)&Kt[row * Ss + col] = kc;
            *(f16x4*)&Vt[row * Ss + col] = vc;
        }
    }
    __syncthreads();

    // ---- V^T image export (verbatim swizzled dump) ----
#pragma unroll
    for (int p = 0; p < 4; p++)
        *(f16x8*)&vimgw[(size_t)(p * 512 + tid) * 8] =
            *(const f16x8*)&Vt[(p * 512 + tid) * 8];

    // ---- ksum: per-row reduction of Kt (threads 0..127) ----
    if (tid < Ss) {
        int sw = (tid & 15) << 3;
        float s = 0.f;
#pragma unroll
        for (int i = 0; i < 16; i++) {
            f16x8 ld = *(const f16x8*)&Kt[tid * Ss + ((8 * i) ^ sw)];
#pragma unroll
            for (int e = 0; e < 8; e++) s += (float)ld[e];
        }
        ws[OFF_KSUM + (size_t)blk * Kk + tid] = s;
    }

    // ---- MFMA (swapped): wave w -> vidx band [16w, 16w+16) ----
    const int band = w * 16;
    const int swt = l15 << 3;
    f16x8 af[4];
#pragma unroll
    for (int kk = 0; kk < 4; kk++)
        af[kk] = *(const f16x8*)&Vt[(band + l15) * Ss + ((kk * 32 + g * 8) ^ swt)];

    f32x4 acc[8];
#pragma unroll
    for (int kj = 0; kj < 8; kj++) acc[kj] = (f32x4){0.f, 0.f, 0.f, 0.f};

    __builtin_amdgcn_s_setprio(1);
#pragma unroll
    for (int kj = 0; kj < 8; kj++) {
        int kr = kj * 16 + l15;
#pragma unroll
        for (int kk = 0; kk < 4; kk++) {
            f16x8 bv = *(const f16x8*)&Kt[kr * Ss + ((kk * 32 + g * 8) ^ swt)];
            acc[kj] = __builtin_amdgcn_mfma_f32_16x16x32_f16(af[kk], bv, acc[kj], 0, 0, 0);
        }
    }
    __builtin_amdgcn_s_setprio(0);

    // ---- write kv^T fp16, SWIZZLED [v][k ^ ((v&15)<<3)] ----
    _Float16* dst = (_Float16*)(ws + OFF_KVH) + (size_t)blk * Kk * Vv;
#pragma unroll
    for (int kj = 0; kj < 8; kj++)
#pragma unroll
        for (int r = 0; r < 4; r++) {
            int vrow = band + 4 * g + r;
            int col = (kj * 16 + l15) ^ ((vrow & 15) << 3);
            dst[(size_t)vrow * Kk + col] = (_Float16)acc[kj][r];
        }
}

// ---------------------------------------------------------------------------
// Kernel 2: scan application on SWIZZLED kv^T, f16x4 granularity (8B RMW
// transactions, half the chain count vs f16x2). Coefficients block-local.
// ---------------------------------------------------------------------------
__global__ __launch_bounds__(128) void k_scan_apply(const float* __restrict__ C0,
                                                    const float* __restrict__ n0,
                                                    const float* __restrict__ m0,
                                                    float* __restrict__ ws) {
    __shared__ float se1[Cc], se2[Cc];
    const int NC4 = BH * Kk * Vv / 4;     // 65536 f16x4 chains
    int gid = blockIdx.x * 128 + threadIdx.x;
    bool main_r = gid < NC4;
    int bh = main_r ? (gid >> 12) : ((gid - NC4) >> 7);

    if (threadIdx.x < Cc) {
        int cc = threadIdx.x;
        float m   = m0[bh];
        float lfl = ws[OFF_LFLAST + bh * Cc + cc];
        float mi  = ws[OFF_MINTRA + bh * Cc + cc];
        float mn  = fmaxf(lfl + m, mi);
        se1[cc] = __expf(lfl + m - mn);
        se2[cc] = __expf(mi - mn);
    }
    __syncthreads();

    if (main_r) {
        int i  = gid & 4095;
        int v  = i >> 5;
        int j4 = (i & 31) << 2;                 // stored position (4-aligned)
        int klog = j4 ^ ((v & 15) << 3);        // logical k base (4 contiguous)
        const float* c0p = C0 + (size_t)bh * Kk * Vv + (size_t)klog * Vv + v;
        float st0 = c0p[0];
        float st1 = c0p[Vv];
        float st2 = c0p[2 * Vv];
        float st3 = c0p[3 * Vv];
        f16x4* base = (f16x4*)((_Float16*)(ws + OFF_KVH) +
                               (size_t)bh * Cc * Kk * Vv + (size_t)v * Kk + j4);
        const size_t stride = Kk * Vv / 4;
        f16x4 cur = base[0];
        f16x4 nxt = base[stride];
#pragma unroll
        for (int c = 0; c < Cc; c++) {
            f16x4 n2 = (c + 2 < Cc) ? base[(size_t)(c + 2) * stride]
                                    : (f16x4){(_Float16)0.f, (_Float16)0.f,
                                              (_Float16)0.f, (_Float16)0.f};
            f16x4 o = { (_Float16)st0, (_Float16)st1, (_Float16)st2, (_Float16)st3 };
            base[(size_t)c * stride] = o;          // c_prev^T for chunk c
            float e1 = se1[c], e2 = se2[c];
            st0 = st0 * e1 + (float)cur[0] * e2;
            st1 = st1 * e1 + (float)cur[1] * e2;
            st2 = st2 * e1 + (float)cur[2] * e2;
            st3 = st3 * e1 + (float)cur[3] * e2;
            cur = nxt; nxt = n2;
        }
    } else if (gid < NC4 + BH * Kk) {
        int g2 = gid - NC4;
        float st = n0[g2];
        float* base = ws + OFF_KSUM + (size_t)bh * Cc * Kk + (g2 & (Kk - 1));
        float cur = base[0];
        float nxt = base[Kk];
#pragma unroll
        for (int c = 0; c < Cc; c++) {
            float n2 = (c + 2 < Cc) ? base[(size_t)(c + 2) * Kk] : 0.f;
            float kvv = cur;
            base[(size_t)c * Kk] = st;             // n_prev for chunk c
            st = st * se1[c] + kvv * se2[c];
            cur = nxt; nxt = n2;
        }
    }
}

// ---------------------------------------------------------------------------
// Kernel 3 (v7): images via global_load_lds; c_prev^T restaged into dead XbK;
// swapped QK^T (P lane-local) + swapped PV (float4 stores); 4 barriers.
// ---------------------------------------------------------------------------
__global__ __launch_bounds__(512, 4) void k_out_mfma(const float* __restrict__ qg,
                                                     const float* __restrict__ ig,
                                                     const float* __restrict__ m0,
                                                     float* __restrict__ ws,
                                                     float* __restrict__ out) {
    __shared__ _Float16 XbK[Ss * Kk];   // K image [t][k^sw]; later c_prev^T
    __shared__ _Float16 XbV[Ss * Kk];   // V^T image [v][t^sw]
    __shared__ float sbt[Ss], sas[Ss], siw[Ss], slfa[Ss], snp[Ss];
    __shared__ float scomb[2];

    int blk = blockIdx.x;
    int bh = blk >> 5;
    int c  = blk & 31;
    int tid = threadIdx.x;
    int lane = tid & 63;
    int w = tid >> 6;                   // wave id 0..7; owns s in [16w,16w+16)
    int l15 = lane & 15;
    int g = lane >> 4;                  // 0..3
    const int S0 = w * 16;
    const int swt = l15 << 3;

    const size_t rowbase = (size_t)bh * Tt + (size_t)c * Ss;
    const float* qp = qg + rowbase * Kk;
    const float* nprev = ws + OFF_KSUM + (size_t)blk * Kk;
    const _Float16* cprevT = (const _Float16*)(ws + OFF_KVH) + (size_t)blk * Kk * Vv;
    const _Float16* kimg = (const _Float16*)(ws + OFF_KIMG) + (size_t)blk * Ss * Kk;
    const _Float16* vimg = (const _Float16*)(ws + OFF_VIMG) + (size_t)blk * Ss * Kk;
    const float m_prev = m0[bh];        // reference quirk: m never rebinds

    // ---- async image loads: HBM/L2 -> LDS, 16B/lane, wave-uniform base ----
#pragma unroll
    for (int p = 0; p < 4; p++) {
        int unit = p * 512 + w * 64;                 // wave-uniform
        GLDS16(kimg + (size_t)(unit + lane) * 8, &XbK[unit * 8]);
        GLDS16(vimg + (size_t)(unit + lane) * 8, &XbV[unit * 8]);
    }

    // ---- Q fragments: qf[kk][e] = q[S0+l15][kk*32+g*8+e] ----
    f16x8 qf[4];
#pragma unroll
    for (int kk = 0; kk < 4; kk++) {
        const float* p = qp + (size_t)(S0 + l15) * Kk + kk * 32 + g * 8;
        float4 a = *(const float4*)p;
        float4 b = *(const float4*)(p + 4);
        f16x8 r;
        r[0]=(_Float16)a.x; r[1]=(_Float16)a.y; r[2]=(_Float16)a.z; r[3]=(_Float16)a.w;
        r[4]=(_Float16)b.x; r[5]=(_Float16)b.y; r[6]=(_Float16)b.z; r[7]=(_Float16)b.w;
        qf[kk] = r;
    }

    // ---- phase 0 part 1: bt + prefix max (threads 0..127) ----
    bool p0 = tid < Ss;
    int lane64 = tid & 63;
    int wv = (tid >> 6) & 1;
    float pm = 0.f;
    if (p0) {
        float lfa = ws[OFF_LFACC + bh * Tt + c * Ss + tid];
        float bt = ig[bh * Tt + c * Ss + tid] - lfa;
        sbt[tid] = bt;
        slfa[tid] = lfa;
        snp[tid] = nprev[tid];
        pm = bt;
        for (int off = 1; off < 64; off <<= 1) {
            float o = __shfl_up(pm, off);
            if (lane64 >= off) pm = fmaxf(pm, o);
        }
        if (lane64 == 63) scomb[wv] = pm;
    }
    __syncthreads();   // barrier A: images in LDS, sbt/slfa/snp/scomb ready

    if (p0) {
        if (wv == 1) pm = fmaxf(pm, scomb[0]);
        float mx = fmaxf(pm, m_prev);
        sas[tid] = -mx;
        siw[tid] = SCALE * __expf(m_prev - mx);
    }
    // intern raw dot: q[s].n_prev, s = S0+l15
    float dotq = 0.f;
#pragma unroll
    for (int kk = 0; kk < 4; kk++)
#pragma unroll
        for (int e = 0; e < 8; e++)
            dotq += (float)qf[kk][e] * snp[kk * 32 + g * 8 + e];
    dotq += __shfl_xor(dotq, 16);
    dotq += __shfl_xor(dotq, 32);
    __syncthreads();   // barrier B: sas/siw ready

    const float as_s = sas[S0 + l15];
    const float iw_s = siw[S0 + l15];
    const float lfa_s = slfa[S0 + l15];

    // ---- swapped QK^T: lane gets P[s=S0+l15][t=16tj+4g+r] ----
    unsigned plo[8] = {0,0,0,0,0,0,0,0};
    unsigned phi[8] = {0,0,0,0,0,0,0,0};
    float rs = 0.f;
#pragma unroll
    for (int tj = 0; tj < 8; tj++) {
        if (tj <= w) {
            int trow = tj * 16 + l15;
            f16x8 bfr[4];
#pragma unroll
            for (int kk = 0; kk < 4; kk++)
                bfr[kk] = *(const f16x8*)&XbK[trow * Kk + ((kk * 32 + g * 8) ^ swt)];
            f32x4 acc = {0.f, 0.f, 0.f, 0.f};
            __builtin_amdgcn_s_setprio(1);
#pragma unroll
            for (int kk = 0; kk < 4; kk++)
                acc = __builtin_amdgcn_mfma_f32_16x16x32_f16(bfr[kk], qf[kk], acc, 0, 0, 0);
            __builtin_amdgcn_s_setprio(0);
            float vals[4];
#pragma unroll
            for (int r = 0; r < 4; r++) {
                int t = tj * 16 + 4 * g + r;
                float btv = sbt[t];
                float val = acc[r] * SCALE * __expf(as_s + btv);
                if (tj == w && (4 * g + r) > l15) val = 0.f;   // causal mask
                rs += val;
                vals[r] = val;
            }
            U2 lo, hi;
            lo.h = (f16x2){ (_Float16)vals[0], (_Float16)vals[1] };
            hi.h = (f16x2){ (_Float16)vals[2], (_Float16)vals[3] };
            plo[tj] = lo.u;
            phi[tj] = hi.u;
        }
    }
    // full row sum + M_norm, all in registers
    rs += __shfl_xor(rs, 16);
    rs += __shfl_xor(rs, 32);
    float engs = __expf(as_s - lfa_s);              // exp(-(lfa+mx))
    float rnv_s = 1.0f / fmaxf(fabsf(rs + dotq * iw_s), engs);
    __syncthreads();   // barrier C: all QK^T reads of XbK done

    // ---- stage c_prev^T into XbK space (async; hidden under pb + PV) ----
#pragma unroll
    for (int p = 0; p < 4; p++) {
        int u = w * 4 + p;                           // wave-uniform
        GLDS16(cprevT + (size_t)(u * 64 + lane) * 8, &XbK[u * 512]);
    }

    // ---- P -> B-operand fragments via cross-g shfl exchange ----
    f16x8 pb[4];
    const int kmax = w >> 1;
    {
        int a2 = (g & 1) * 2;
        int sA = a2 * 16 + l15;
        int sB = sA + 16;
        bool hi2 = (g >> 1) != 0;
#pragma unroll
        for (int kkt = 0; kkt < 4; kkt++) {
            if (kkt <= kmax) {
                unsigned xA0 = __shfl((int)plo[2*kkt],   sA);
                unsigned xA1 = __shfl((int)phi[2*kkt],   sA);
                unsigned xB0 = __shfl((int)plo[2*kkt],   sB);
                unsigned xB1 = __shfl((int)phi[2*kkt],   sB);
                unsigned yA0 = __shfl((int)plo[2*kkt+1], sA);
                unsigned yA1 = __shfl((int)phi[2*kkt+1], sA);
                unsigned yB0 = __shfl((int)plo[2*kkt+1], sB);
                unsigned yB1 = __shfl((int)phi[2*kkt+1], sB);
                U8 t;
                t.u[0] = hi2 ? yA0 : xA0;
                t.u[1] = hi2 ? yA1 : xA1;
                t.u[2] = hi2 ? yB0 : xB0;
                t.u[3] = hi2 ? yB1 : xB1;
                pb[kkt] = t.v;
            }
        }
    }

    // ---- PV for BOTH halves (reads XbV only; covers c_prev load latency) ----
    f32x4 h4[2][4];
#pragma unroll
    for (int half = 0; half < 2; half++)
#pragma unroll
        for (int j = 0; j < 4; j++) h4[half][j] = (f32x4){0.f, 0.f, 0.f, 0.f};

    __builtin_amdgcn_s_setprio(1);
#pragma unroll
    for (int kkt = 0; kkt < 4; kkt++) {
        if (kkt <= kmax) {
#pragma unroll
            for (int half = 0; half < 2; half++)
#pragma unroll
                for (int j = 0; j < 4; j++) {
                    int vr = (half * 4 + j) * 16 + l15;
                    f16x8 av = *(const f16x8*)&XbV[vr * Ss + ((kkt * 32 + g * 8) ^ swt)];
                    h4[half][j] = __builtin_amdgcn_mfma_f32_16x16x32_f16(av, pb[kkt], h4[half][j], 0, 0, 0);
                }
        }
    }
    __builtin_amdgcn_s_setprio(0);

    asm volatile("s_waitcnt vmcnt(0)" ::: "memory");
    __syncthreads();   // barrier D: c_prev^T staged in XbK

    // ---- inter (LDS, swizzled) + combine + float4 stores ----
#pragma unroll
    for (int half = 0; half < 2; half++)
#pragma unroll
        for (int j = 0; j < 4; j++) {
            int vr = (half * 4 + j) * 16 + l15;
            f32x4 tmp = {0.f, 0.f, 0.f, 0.f};
            int swv = (vr & 15) << 3;
#pragma unroll
            for (int kk = 0; kk < 4; kk++) {
                f16x8 bcf = *(const f16x8*)&XbK[vr * Kk + ((kk * 32 + g * 8) ^ swv)];
                tmp = __builtin_amdgcn_mfma_f32_16x16x32_f16(bcf, qf[kk], tmp, 0, 0, 0);
            }
            float4 o;
            o.x = (h4[half][j][0] + tmp[0] * iw_s) * rnv_s;
            o.y = (h4[half][j][1] + tmp[1] * iw_s) * rnv_s;
            o.z = (h4[half][j][2] + tmp[2] * iw_s) * rnv_s;
            o.w = (h4[half][j][3] + tmp[3] * iw_s) * rnv_s;
            *(float4*)&out[(rowbase + S0 + l15) * Vv + (half * 4 + j) * 16 + 4 * g] = o;
        }
}

// ---------------------------------------------------------------------------
extern "C" void kernel_launch(void* const* d_in, const int* in_sizes, int n_in,
                              void* d_out, int out_size, void* d_ws, size_t ws_size,
                              hipStream_t stream) {
    (void)in_sizes; (void)n_in; (void)out_size; (void)ws_size;
    const float* q  = (const float*)d_in[0];
    const float* k  = (const float*)d_in[1];
    const float* v  = (const float*)d_in[2];
    const float* ig = (const float*)d_in[3];
    const float* fg = (const float*)d_in[4];
    const float* C0 = (const float*)d_in[5];
    const float* n0 = (const float*)d_in[6];
    const float* m0 = (const float*)d_in[7];
    float* out = (float*)d_out;
    float* ws  = (float*)d_ws;

    k_kvg<<<BH * Cc, 512, 0, stream>>>(ig, fg, k, v, ws);
    k_scan_apply<<<(BH * Kk * Vv / 4 + BH * Kk) / 128, 128, 0, stream>>>(C0, n0, m0, ws);
    k_out_mfma<<<BH * Cc, 512, 0, stream>>>(q, ig, m0, ws, out);
}